// Round 4
// baseline (14.556 us; speedup 1.0000x reference)
//
#include <hip/hip_runtime.h>
#include <hip/hip_bf16.h>

// Problem: B=8192, S=8, D=96.
// Math collapses (softmax over axis=1 sums to 1; both einsums are rank-1
// outer products of sequence-sums):
//   out[b,s,d] = sum_e (x[b,s,e] + pos[s]) * col[e]      for ALL d
// where col[e] = sum_n Wv[n,e],  pos[s] = sum_j j*Wp[s,j] + bp[s].
// Wk, Wq, softmax, and both einsums cancel.
//
// Single fused kernel, 512 blocks x 1024 threads, ONE 12-float chunk per
// thread -> low VGPR -> 2 blocks/CU = 32 waves/CU (max occupancy). Per-block
// setup: 768 threads sum 3 rows of Wv each (coalesced float4), LDS
// tree-reduce -> col[96]; x loads issued before setup so HBM latency hides
// under it. Interleaved layout: the 8 lanes of a row take float4s at
// sub*4 + j*32, so each 8-lane group's access is one full 128B line.

#define NTHR 1024
#define NBLK 512          // 512 * 1024 = 524288 chunks = 65536 rows * 8

__global__ __launch_bounds__(NTHR) void attn_fused_kernel(
    const float* __restrict__ x, const float* __restrict__ Wp,
    const float* __restrict__ bp, const float* __restrict__ Wv,
    float* __restrict__ out) {
    __shared__ __align__(16) float4 part[32][24];   // 12 KB
    __shared__ __align__(16) float4 col4[24];       // col[96]
    __shared__ float posv[8];

    const int t = threadIdx.x;
    const int c = blockIdx.x * NTHR + t;            // chunk id
    const int row = c >> 3, sub = c & 7;

    // ---- issue x loads FIRST (latency hides under setup) ----
    const float* xb = x + (size_t)row * 96 + sub * 4;
    float4 a0 = *(const float4*)(xb);
    float4 a1 = *(const float4*)(xb + 32);
    float4 a2 = *(const float4*)(xb + 64);

    // ---- parallel setup: col[e] = sum_n Wv[n,e] ----
    const float4* Wv4 = (const float4*)Wv;          // [96 rows][24 slots]
    if (t < 768) {
        const int slot = t % 24;
        const int g    = t / 24;                    // 0..31, 3 rows each
        const int n0   = g * 3;
        float4 s0 = Wv4[(n0 + 0) * 24 + slot];
        float4 s1 = Wv4[(n0 + 1) * 24 + slot];
        float4 s2 = Wv4[(n0 + 2) * 24 + slot];
        part[g][slot] = make_float4(s0.x + s1.x + s2.x, s0.y + s1.y + s2.y,
                                    s0.z + s1.z + s2.z, s0.w + s1.w + s2.w);
    } else if (t < 776) {
        const int s = t - 768;
        float p = bp[s];
        #pragma unroll
        for (int j = 1; j < 8; ++j) p += (float)j * Wp[s * 8 + j];
        posv[s] = p;
    }
    __syncthreads();
    if (t < 24) {
        float4 cc = part[0][t];
        #pragma unroll
        for (int g = 1; g < 32; ++g) {
            float4 q = part[g][t];
            cc.x += q.x; cc.y += q.y; cc.z += q.z; cc.w += q.w;
        }
        col4[t] = cc;
    }
    __syncthreads();

    // ---- dot + broadcast-store ----
    float4 w0 = col4[sub + 0], w1 = col4[sub + 8], w2 = col4[sub + 16];
    const float p = posv[row & 7];
    float dot = (a0.x + p) * w0.x + (a0.y + p) * w0.y + (a0.z + p) * w0.z + (a0.w + p) * w0.w
              + (a1.x + p) * w1.x + (a1.y + p) * w1.y + (a1.z + p) * w1.z + (a1.w + p) * w1.w
              + (a2.x + p) * w2.x + (a2.y + p) * w2.y + (a2.z + p) * w2.z + (a2.w + p) * w2.w;
    dot += __shfl_xor(dot, 1);
    dot += __shfl_xor(dot, 2);
    dot += __shfl_xor(dot, 4);
    float4 v = make_float4(dot, dot, dot, dot);
    float* ob = out + (size_t)row * 96 + sub * 4;
    *(float4*)(ob)      = v;
    *(float4*)(ob + 32) = v;
    *(float4*)(ob + 64) = v;
}

extern "C" void kernel_launch(void* const* d_in, const int* in_sizes, int n_in,
                              void* d_out, int out_size, void* d_ws, size_t ws_size,
                              hipStream_t stream) {
    const float* x  = (const float*)d_in[0];
    const float* Wp = (const float*)d_in[1];
    const float* bp = (const float*)d_in[2];
    const float* Wv = (const float*)d_in[3];
    // Wk (d_in[4]) and Wq (d_in[5]) cancel out of the math entirely.
    float* out = (float*)d_out;

    attn_fused_kernel<<<NBLK, NTHR, 0, stream>>>(x, Wp, bp, Wv, out);
}